// Round 1
// baseline (617.741 us; speedup 1.0000x reference)
//
#include <hip/hip_runtime.h>
#include <hip/hip_bf16.h>
#include <cmath>

#define N_TOKENS 16384
#define D_MODEL  4096
#define NE       8
#define CAPACITY 2048
#define NITEMS   (N_TOKENS * 2)

// ---- kernel 1 geometry ----
#define T_PER_WAVE 8
#define K1_BLOCK   256
#define K1_WAVES   (K1_BLOCK / 64)
#define K1_GRID    (N_TOKENS / (T_PER_WAVE * K1_WAVES))   // 512

// ws layout (in 4-byte words)
// probs   [32768] @ 0
// eids    [32768] @ 32768
// tiekeep [32768] @ 65536
// zpart   [512]   @ 98304
// usage   [8]     @ 98816
// thresh  [8]     @ 98824

__global__ __launch_bounds__(K1_BLOCK) void k1_gemv_top2(
    const float* __restrict__ x, const float* __restrict__ w,
    float* __restrict__ probs, int* __restrict__ eids,
    int* __restrict__ tiekeep, float* __restrict__ zpart)
{
    const int wave = (blockIdx.x * K1_BLOCK + threadIdx.x) >> 6;
    const int lane = threadIdx.x & 63;
    const int tok0 = wave * T_PER_WAVE;

    float acc[T_PER_WAVE][NE];
#pragma unroll
    for (int t = 0; t < T_PER_WAVE; ++t)
#pragma unroll
        for (int e = 0; e < NE; ++e) acc[t][e] = 0.f;

    const int dbase = lane * 4;
#pragma unroll 1
    for (int it = 0; it < D_MODEL / 256; ++it) {
        const int d = it * 256 + dbase;
        float4 xv[T_PER_WAVE];
#pragma unroll
        for (int t = 0; t < T_PER_WAVE; ++t)
            xv[t] = *reinterpret_cast<const float4*>(x + (size_t)(tok0 + t) * D_MODEL + d);
#pragma unroll
        for (int e = 0; e < NE; ++e) {
            const float4 wv = *reinterpret_cast<const float4*>(w + (size_t)e * D_MODEL + d);
#pragma unroll
            for (int t = 0; t < T_PER_WAVE; ++t) {
                acc[t][e] += xv[t].x * wv.x;
                acc[t][e] += xv[t].y * wv.y;
                acc[t][e] += xv[t].z * wv.z;
                acc[t][e] += xv[t].w * wv.w;
            }
        }
    }

    // butterfly all-reduce each accumulator across the 64-lane wave
#pragma unroll
    for (int t = 0; t < T_PER_WAVE; ++t)
#pragma unroll
        for (int e = 0; e < NE; ++e) {
#pragma unroll
            for (int m = 1; m < 64; m <<= 1)
                acc[t][e] += __shfl_xor(acc[t][e], m, 64);
        }

    float zv = 0.f;
    // lane t handles token tok0+t (compile-time t via unroll => register indexing)
#pragma unroll
    for (int t = 0; t < T_PER_WAVE; ++t) {
        if (lane == t) {
            float l[NE];
#pragma unroll
            for (int e = 0; e < NE; ++e) l[e] = acc[t][e];
            // top-1: strict > keeps lowest index on ties (jax.lax.top_k stable)
            int e1 = 0; float m1 = l[0];
#pragma unroll
            for (int e = 1; e < NE; ++e) { if (l[e] > m1) { m1 = l[e]; e1 = e; } }
            int e2 = -1; float m2 = -INFINITY;
#pragma unroll
            for (int e = 0; e < NE; ++e) { if (e != e1 && l[e] > m2) { m2 = l[e]; e2 = e; } }
            // softmax over [m1, m2] then renormalize (mirror reference arithmetic)
            const float tt = expf(m2 - m1);
            const float s1 = 1.f / (1.f + tt);
            const float s2 = tt / (1.f + tt);
            const float inv = 1.f / (s1 + s2);
            const float p1 = s1 * inv, p2 = s2 * inv;
            // z-loss: logsumexp^2
            float sum = 0.f;
#pragma unroll
            for (int e = 0; e < NE; ++e) sum += expf(l[e] - m1);
            const float lse = m1 + logf(sum);
            zv = lse * lse;

            const int i0 = (tok0 + t) * 2;
            probs[i0] = p1;  probs[i0 + 1] = p2;
            eids[i0]  = e1;  eids[i0 + 1]  = e2;
            tiekeep[i0] = 0; tiekeep[i0 + 1] = 0;
        }
    }

    // per-block z partial (deterministic-ish; no global atomic contention)
#pragma unroll
    for (int m = 1; m < 64; m <<= 1) zv += __shfl_xor(zv, m, 64);
    __shared__ float zs[K1_WAVES];
    if (lane == 0) zs[threadIdx.x >> 6] = zv;
    __syncthreads();
    if (threadIdx.x == 0) {
        float s = 0.f;
        for (int i = 0; i < K1_WAVES; ++i) s += zs[i];
        zpart[blockIdx.x] = s;
    }
}

// ---- kernel 2: per-expert exact radix select (threshold + tie ranks) ----
__global__ __launch_bounds__(256) void k2_select(
    const float* __restrict__ probs, const int* __restrict__ eids,
    unsigned* __restrict__ thresh, int* __restrict__ tiekeep,
    int* __restrict__ usage)
{
    const int e = blockIdx.x;
    const int tid = threadIdx.x;
    if (tid == 0) usage[e] = 0;   // zero-init for k3's atomics

    __shared__ unsigned hist[256];
    __shared__ unsigned s_prefix;
    __shared__ int s_need, s_done;
    if (tid == 0) { s_prefix = 0u; s_need = CAPACITY; s_done = 0; }
    __syncthreads();

    for (int round = 0; round < 4; ++round) {
        hist[tid] = 0u;
        __syncthreads();
        const int shift = 24 - 8 * round;
        const unsigned pref = s_prefix;
        const int done = s_done;
        if (!done) {
            for (int i = tid; i < NITEMS; i += 256) {
                if (eids[i] == e) {
                    const unsigned b = __float_as_uint(probs[i]);
                    const bool match = (round == 0) ||
                                       ((b >> (shift + 8)) == (pref >> (shift + 8)));
                    if (match) atomicAdd(&hist[(b >> shift) & 255u], 1u);
                }
            }
        }
        __syncthreads();
        if (tid == 0 && !done) {
            int need = s_need; unsigned acc = 0; int picked = -1;
            for (int v = 255; v >= 0; --v) {
                const unsigned h = hist[v];
                if (acc + h >= (unsigned)need) {
                    picked = v;
                    s_prefix = pref | ((unsigned)v << shift);
                    s_need = need - (int)acc;
                    break;
                }
                acc += h;
            }
            if (picked < 0) { s_done = 1; s_prefix = 0u; s_need = 0; } // n_e < CAP: keep all
        }
        __syncthreads();
    }

    const unsigned Tval = s_prefix;
    const int need = s_need;
    if (tid == 0) thresh[e] = Tval;
    if (s_done) return;  // keep-all: bits > 0 keeps everything (probs are > 0)

    // tie pass: items exactly at threshold — keep the `need` smallest flat indices
    __shared__ int tcnt;
    __shared__ int tlist[2048];
    if (tid == 0) tcnt = 0;
    __syncthreads();
    for (int i = tid; i < NITEMS; i += 256) {
        if (eids[i] == e && __float_as_uint(probs[i]) == Tval) {
            const int p = atomicAdd(&tcnt, 1);
            if (p < 2048) tlist[p] = i;
        }
    }
    __syncthreads();
    const int tc = tcnt < 2048 ? tcnt : 2048;
    for (int k = tid; k < tc; k += 256) {
        const int i = tlist[k];
        int r = 0;
        for (int j = 0; j < tc; ++j) r += (tlist[j] < i) ? 1 : 0;
        tiekeep[i] = (r < need) ? 1 : 0;
    }
}

// ---- kernel 3: apply keep mask, write outputs, histogram usage ----
__global__ __launch_bounds__(256) void k3_apply(
    const float* __restrict__ probs, const int* __restrict__ eids,
    const unsigned* __restrict__ thresh, const int* __restrict__ tiekeep,
    float* __restrict__ out_idx, float* __restrict__ out_prob,
    int* __restrict__ usage)
{
    __shared__ int h[NE];
    const int tid = threadIdx.x;
    if (tid < NE) h[tid] = 0;
    __syncthreads();

    const int i = blockIdx.x * 256 + tid;
    const int e = eids[i];
    const float p = probs[i];
    const unsigned b = __float_as_uint(p);
    const unsigned tv = thresh[e];
    const bool keep = (b > tv) || (b == tv && tiekeep[i]);
    const int oi = keep ? e : 0;            // dropped -> index 0 (reference semantics)
    out_idx[i]  = (float)oi;
    out_prob[i] = keep ? p : 0.f;
    atomicAdd(&h[oi], 1);
    __syncthreads();
    if (tid < NE) atomicAdd(&usage[tid], h[tid]);
}

// ---- kernel 4: finalize losses ----
__global__ __launch_bounds__(512) void k4_final(
    const float* __restrict__ zpart, const int* __restrict__ usage,
    float* __restrict__ out)
{
    const int tid = threadIdx.x;
    float z = zpart[tid];           // 512 partials, 512 threads
#pragma unroll
    for (int m = 1; m < 64; m <<= 1) z += __shfl_xor(z, m, 64);
    __shared__ float zp[8];
    if ((tid & 63) == 0) zp[tid >> 6] = z;
    __syncthreads();
    if (tid == 0) {
        float zs = 0.f;
        for (int i = 0; i < 8; ++i) zs += zp[i];
        const float z_loss = zs / (float)N_TOKENS;
        const float ideal = (float)(N_TOKENS * 2 / NE);   // 4096
        float lb = 0.f;
        for (int e = 0; e < NE; ++e) {
            const float d = (float)usage[e] - ideal;
            lb += d * d;
        }
        lb /= (float)NE;
        out[65536] = lb;
        out[65537] = z_loss;
        for (int e = 0; e < NE; ++e) out[65538 + e] = (float)usage[e];
    }
}

extern "C" void kernel_launch(void* const* d_in, const int* in_sizes, int n_in,
                              void* d_out, int out_size, void* d_ws, size_t ws_size,
                              hipStream_t stream)
{
    const float* x = (const float*)d_in[0];       // [16384, 4096]
    const float* w = (const float*)d_in[1];       // [8, 4096]
    float* out = (float*)d_out;

    float*    ws_probs   = (float*)d_ws;                  // [32768]
    int*      ws_eids    = (int*)d_ws + 32768;            // [32768]
    int*      ws_tiekeep = (int*)d_ws + 65536;            // [32768]
    float*    ws_zpart   = (float*)d_ws + 98304;          // [512]
    int*      ws_usage   = (int*)d_ws + 98816;            // [8]
    unsigned* ws_thresh  = (unsigned*)d_ws + 98824;       // [8]

    float* out_idx  = out;            // [32768]
    float* out_prob = out + 32768;    // [32768]

    k1_gemv_top2<<<K1_GRID, K1_BLOCK, 0, stream>>>(
        x, w, ws_probs, ws_eids, ws_tiekeep, ws_zpart);
    k2_select<<<NE, 256, 0, stream>>>(
        ws_probs, ws_eids, ws_thresh, ws_tiekeep, ws_usage);
    k3_apply<<<NITEMS / 256, 256, 0, stream>>>(
        ws_probs, ws_eids, ws_thresh, ws_tiekeep, out_idx, out_prob, ws_usage);
    k4_final<<<1, 512, 0, stream>>>(ws_zpart, ws_usage, out);
}

// Round 3
// 425.330 us; speedup vs baseline: 1.4524x; 1.4524x over previous
//
#include <hip/hip_runtime.h>
#include <hip/hip_bf16.h>
#include <cmath>

#define N_TOKENS 16384
#define D_MODEL  4096
#define NE       8
#define CAPACITY 2048
#define NITEMS   (N_TOKENS * 2)

// ---- kernel 1 geometry ----
#define T_PER_WAVE 4
#define K1_BLOCK   256
#define K1_WAVES   (K1_BLOCK / 64)
#define K1_TOKPB   (T_PER_WAVE * K1_WAVES)          // 16 tokens per block
#define K1_GRID    (N_TOKENS / K1_TOKPB)            // 1024

#define NBINS      8192                             // 13-bit key = float_bits >> 19

// ---- ws layout (4-byte words) ----
// hist    [8*8192 = 65536] @ 0          (memset 0)
// cnt     [1]              @ 65536      (memset 0)
// usage   [8]              @ 65537      (memset 0)
// bucket  [8]              @ 65545
// need    [8]              @ 65553
// pad                      @ 65561..65567
// zpart   [1024]           @ 65568
// keep    [32768 bytes]    @ 66592      (8192 words)
// list    [32768 uint2]    @ 74784      (65536 words)
// total: 140320 words = 561,280 bytes

__global__ __launch_bounds__(K1_BLOCK) void k1_gemv_top2(
    const float* __restrict__ x, const float* __restrict__ w,
    float* __restrict__ out_idx, float* __restrict__ out_prob,
    unsigned* __restrict__ hist, float* __restrict__ zpart)
{
    const int lane = threadIdx.x & 63;
    const int wave = blockIdx.x * K1_WAVES + (threadIdx.x >> 6);
    const int tok0 = wave * T_PER_WAVE;

    float acc[T_PER_WAVE][NE];
#pragma unroll
    for (int t = 0; t < T_PER_WAVE; ++t)
#pragma unroll
        for (int e = 0; e < NE; ++e) acc[t][e] = 0.f;

    const int dbase = lane * 4;
#pragma unroll 1
    for (int it = 0; it < D_MODEL / 256; ++it) {
        const int d = it * 256 + dbase;
        float4 xv[T_PER_WAVE];
#pragma unroll
        for (int t = 0; t < T_PER_WAVE; ++t)
            xv[t] = *reinterpret_cast<const float4*>(x + (size_t)(tok0 + t) * D_MODEL + d);
#pragma unroll
        for (int e = 0; e < NE; ++e) {
            const float4 wv = *reinterpret_cast<const float4*>(w + (size_t)e * D_MODEL + d);
#pragma unroll
            for (int t = 0; t < T_PER_WAVE; ++t) {
                acc[t][e] += xv[t].x * wv.x;
                acc[t][e] += xv[t].y * wv.y;
                acc[t][e] += xv[t].z * wv.z;
                acc[t][e] += xv[t].w * wv.w;
            }
        }
    }

    // ---- pair-merge exchange reduction: 31 shuffles + 1 cross-half ----
    // invariant: before step b, r[i] holds partial for j = (i<<b) | (lane & ((1<<b)-1)),
    // summed over lanes sharing low b bits. After 5 steps + cross-half,
    // lane l owns the full sum for j = l & 31, i.e. (t,e) = ((l&31)>>3, l&7).
    float r[32];
#pragma unroll
    for (int j = 0; j < 32; ++j) r[j] = acc[j >> 3][j & 7];
#pragma unroll
    for (int b = 0; b < 5; ++b) {
        const int bit = 1 << b;
        const bool up = (lane & bit) != 0;
#pragma unroll
        for (int q = 0; q < (32 >> (b + 1)); ++q) {
            const float a = r[2 * q];       // j-bit-b == 0
            const float c = r[2 * q + 1];   // j-bit-b == 1
            const float kept = up ? c : a;
            const float sent = up ? a : c;
            r[q] = kept + __shfl_xor(sent, bit, 64);
        }
    }
    r[0] += __shfl_xor(r[0], 32, 64);

    // broadcast: every lane gathers its token's 8 logits (8 shuffles)
    float lg[NE];
#pragma unroll
    for (int e = 0; e < NE; ++e)
        lg[e] = __shfl(r[0], (lane & 56) | e, 64);

    // all 8 lanes of a token redundantly compute the epilogue
    int e1 = 0; float m1 = lg[0];
#pragma unroll
    for (int e = 1; e < NE; ++e) { if (lg[e] > m1) { m1 = lg[e]; e1 = e; } }
    int e2 = 0; float m2 = -INFINITY;
#pragma unroll
    for (int e = 0; e < NE; ++e) { if (e != e1 && lg[e] > m2) { m2 = lg[e]; e2 = e; } }
    const float tt = expf(m2 - m1);
    const float s1 = 1.f / (1.f + tt);
    const float s2 = tt / (1.f + tt);
    const float inv = 1.f / (s1 + s2);
    const float p1 = s1 * inv, p2 = s2 * inv;
    float sum = 0.f;
#pragma unroll
    for (int e = 0; e < NE; ++e) sum += expf(lg[e] - m1);
    const float lse = m1 + logf(sum);

    float zv = 0.f;
    const int tok = tok0 + ((lane & 31) >> 3);
    if (lane < 32 && (lane & 7) == 0) {
        zv = lse * lse;
        const int i0 = tok * 2;
        out_idx[i0]     = (float)e1;
        out_idx[i0 + 1] = (float)e2;
        out_prob[i0]     = p1;
        out_prob[i0 + 1] = p2;
        atomicAdd(&hist[e1 * NBINS + (__float_as_uint(p1) >> 19)], 1u);
        atomicAdd(&hist[e2 * NBINS + (__float_as_uint(p2) >> 19)], 1u);
    }

    // block z partial
#pragma unroll
    for (int m = 1; m < 64; m <<= 1) zv += __shfl_xor(zv, m, 64);
    __shared__ float zs[K1_WAVES];
    if (lane == 0) zs[threadIdx.x >> 6] = zv;
    __syncthreads();
    if (threadIdx.x == 0) {
        float s = 0.f;
        for (int i = 0; i < K1_WAVES; ++i) s += zs[i];
        zpart[blockIdx.x] = s;
    }
}

// ---- kernel 2: per-expert threshold-bucket find over 8192 bins ----
__global__ __launch_bounds__(256) void k2_bucket(
    const unsigned* __restrict__ hist, int* __restrict__ bucket, int* __restrict__ need)
{
    const int e = blockIdx.x;
    const unsigned* h = hist + e * NBINS;
    const int tid = threadIdx.x;
    // thread t covers bins [hi-31, hi] scanning from the top of the keyspace
    const int hi = NBINS - 1 - 32 * tid;
    unsigned s = 0;
#pragma unroll
    for (int k = 0; k < 32; ++k) s += h[hi - k];
    __shared__ unsigned S[256];
    S[tid] = s;
    __syncthreads();
    if (tid == 0) {
        unsigned cum = 0; int tstar = -1;
        for (int t = 0; t < 256; ++t) {
            if (cum + S[t] >= (unsigned)CAPACITY) { tstar = t; break; }
            cum += S[t];
        }
        if (tstar < 0) { bucket[e] = -1; need[e] = 0; return; }  // n_e <= CAP: keep all
        const int hi2 = NBINS - 1 - 32 * tstar;
        int v = hi2 - 31;
        for (int k = 0; k < 32; ++k) {
            const unsigned hv = h[hi2 - k];
            if (cum + hv >= (unsigned)CAPACITY) { v = hi2 - k; break; }
            cum += hv;
        }
        bucket[e] = v;
        need[e] = CAPACITY - (int)cum;   // how many to keep inside bucket v
    }
}

// ---- kernel 3: classify every assignment; collect threshold-bucket items ----
__global__ __launch_bounds__(256) void k3_classify(
    const float* __restrict__ out_idx, const float* __restrict__ out_prob,
    const int* __restrict__ bucket,
    unsigned char* __restrict__ keep, uint2* __restrict__ list, int* __restrict__ cnt)
{
    const int i = blockIdx.x * 256 + threadIdx.x;
    const int e = (int)out_idx[i];
    const unsigned b = __float_as_uint(out_prob[i]);
    const int key = (int)(b >> 19);
    const int tb = bucket[e];
    unsigned char kp = 0;
    if (tb < 0 || key > tb) kp = 1;
    else if (key == tb) {
        const int pos = atomicAdd(cnt, 1);
        list[pos] = make_uint2(b, (unsigned)i | ((unsigned)e << 20));
        kp = 0;  // provisional; k4_ties decides
    }
    keep[i] = kp;
}

// ---- kernel 4: exact rank inside the threshold bucket (bits desc, idx asc) ----
__global__ __launch_bounds__(256) void k4_ties(
    const uint2* __restrict__ list, const int* __restrict__ cnt,
    const int* __restrict__ bucket, const int* __restrict__ need,
    unsigned char* __restrict__ keep)
{
    const int e = blockIdx.x;
    if (bucket[e] < 0) return;
    const int m = *cnt;
    const int nd = need[e];
    for (int a = threadIdx.x; a < m; a += 256) {
        const uint2 ia = list[a];
        if ((int)(ia.y >> 20) != e) continue;
        const unsigned ib = ia.x;
        const unsigned idx = ia.y & 0xFFFFFu;
        int rnk = 0;
        for (int j = 0; j < m; ++j) {
            const uint2 jb = list[j];
            if ((int)(jb.y >> 20) != e) continue;
            if (jb.x > ib || (jb.x == ib && (jb.y & 0xFFFFFu) < idx)) ++rnk;
        }
        keep[idx] = (rnk < nd) ? 1 : 0;
    }
}

// ---- kernel 5: apply keep mask in-place, histogram usage ----
__global__ __launch_bounds__(256) void k5_apply(
    float* __restrict__ out_idx, float* __restrict__ out_prob,
    const unsigned char* __restrict__ keep, int* __restrict__ usage)
{
    __shared__ int h[NE];
    if (threadIdx.x < NE) h[threadIdx.x] = 0;
    __syncthreads();
    const int i = blockIdx.x * 256 + threadIdx.x;
    const int e = (int)out_idx[i];
    const bool kp = keep[i] != 0;
    if (!kp) { out_idx[i] = 0.f; out_prob[i] = 0.f; }
    atomicAdd(&h[kp ? e : 0], 1);     // dropped -> index 0 (reference semantics)
    __syncthreads();
    if (threadIdx.x < NE) atomicAdd(&usage[threadIdx.x], h[threadIdx.x]);
}

// ---- kernel 6: finalize losses ----
__global__ __launch_bounds__(256) void k6_final(
    const float* __restrict__ zpart, const int* __restrict__ usage,
    float* __restrict__ out)
{
    const int tid = threadIdx.x;
    float z = 0.f;
    for (int i = tid; i < K1_GRID; i += 256) z += zpart[i];
#pragma unroll
    for (int m = 1; m < 64; m <<= 1) z += __shfl_xor(z, m, 64);
    __shared__ float zp[4];
    if ((tid & 63) == 0) zp[tid >> 6] = z;
    __syncthreads();
    if (tid == 0) {
        float zs = 0.f;
        for (int i = 0; i < 4; ++i) zs += zp[i];
        const float z_loss = zs / (float)N_TOKENS;
        const float ideal = (float)(N_TOKENS * 2 / NE);   // 4096
        float lb = 0.f;
        for (int e = 0; e < NE; ++e) {
            const float d = (float)usage[e] - ideal;
            lb += d * d;
        }
        lb /= (float)NE;
        out[65536] = lb;
        out[65537] = z_loss;
        for (int e = 0; e < NE; ++e) out[65538 + e] = (float)usage[e];
    }
}

extern "C" void kernel_launch(void* const* d_in, const int* in_sizes, int n_in,
                              void* d_out, int out_size, void* d_ws, size_t ws_size,
                              hipStream_t stream)
{
    const float* x = (const float*)d_in[0];       // [16384, 4096]
    const float* w = (const float*)d_in[1];       // [8, 4096]
    float* out = (float*)d_out;

    unsigned*      ws_hist   = (unsigned*)d_ws;                    // [65536]
    int*           ws_cnt    = (int*)d_ws + 65536;                 // [1]
    int*           ws_usage  = (int*)d_ws + 65537;                 // [8]
    int*           ws_bucket = (int*)d_ws + 65545;                 // [8]
    int*           ws_need   = (int*)d_ws + 65553;                 // [8]
    float*         ws_zpart  = (float*)d_ws + 65568;               // [1024]
    unsigned char* ws_keep   = (unsigned char*)((int*)d_ws + 66592);  // [32768 B]
    uint2*         ws_list   = (uint2*)((int*)d_ws + 74784);       // [32768]

    float* out_idx  = out;            // [32768]
    float* out_prob = out + 32768;    // [32768]

    // zero hist + cnt + usage (one memset node; graph-capture safe)
    hipMemsetAsync(d_ws, 0, (size_t)65568 * 4, stream);

    k1_gemv_top2<<<K1_GRID, K1_BLOCK, 0, stream>>>(
        x, w, out_idx, out_prob, ws_hist, ws_zpart);
    k2_bucket<<<NE, 256, 0, stream>>>(ws_hist, ws_bucket, ws_need);
    k3_classify<<<NITEMS / 256, 256, 0, stream>>>(
        out_idx, out_prob, ws_bucket, ws_keep, ws_list, ws_cnt);
    k4_ties<<<NE, 256, 0, stream>>>(ws_list, ws_cnt, ws_bucket, ws_need, ws_keep);
    k5_apply<<<NITEMS / 256, 256, 0, stream>>>(out_idx, out_prob, ws_keep, ws_usage);
    k6_final<<<1, 256, 0, stream>>>(ws_zpart, ws_usage, out);
}